// Round 16
// baseline (176.048 us; speedup 1.0000x reference)
//
#include <hip/hip_runtime.h>

// inputs: [M=4096, N=16384] fp32 logits; targets: [M] int32; k = int(0.01*(N-1)) = 163
#define M        4096
#define N        16384
#define K_SEL    163
#define DELTA_W  5.0f
#define NT       256
#define CAPW     512           // per-row candidate cap (mean 372, sd 19; 7.4 sigma)
#define SCALE    4096.0f       // fixed-point for hard-negative sum (order-independent)
#define THRESH   2.0f          // E[count(x>=2)] = 373 per row; 11 sigma above K_SEL

typedef float vfloat4 __attribute__((ext_vector_type(4)));

// Order-preserving float<->uint32 key (ascending float <-> ascending key)
__device__ __forceinline__ unsigned f2key(float x) {
    unsigned u = __float_as_uint(x);
    return u ^ ((unsigned)((int)u >> 31) | 0x80000000u);
}
__device__ __forceinline__ float key2f(unsigned k) {
    unsigned u = k ^ (~(unsigned)((int)k >> 31) | 0x80000000u);
    return __uint_as_float(u);
}
__device__ __forceinline__ void wave_lgkm_wait() {
    asm volatile("s_waitcnt lgkmcnt(0)" ::: "memory");
}

// ---------- Fused kernel: wave-per-row stream -> LDS list -> ballot bit-walk ----------
// Stream (R13-proven): ballot -> uniform SGPR count -> mbcnt rank -> ds_write.
// Select: 32-bit prefix walk, pure VALU/SALU (no LDS hist, no atomics, no shfl scans).
__global__ __launch_bounds__(NT, 4) void fused_row_loss(
    const float* __restrict__ inp, const int* __restrict__ tgt,
    float* __restrict__ row_loss)
{
    __shared__ unsigned hist_all[4][256];   // used by fallback path only
    __shared__ unsigned list_all[4][CAPW];  // wave-private 2 KiB (keys)
    const int lane = threadIdx.x & 63;
    const int wv   = threadIdx.x >> 6;
    const int row  = blockIdx.x * 4 + wv;
    unsigned* hist = hist_all[wv];
    unsigned* list = list_all[wv];
    const float* rp = inp + (size_t)row * N;
    const vfloat4* rp4 = reinterpret_cast<const vfloat4*>(rp);
    const int target = tgt[row];

    // target position decomposition: element t = it*256 + 4*lane + j
    const int it_t = target >> 8;
    const int l_t  = (target & 255) >> 2;
    const int j_t  = target & 3;

    // ---- Phase 1: stream row; push candidates straight to LDS list ----
    unsigned cnt = 0;                        // wave-uniform running candidate count
    #pragma unroll
    for (int it0 = 0; it0 < 64; it0 += 8) {
        vfloat4 v[8];                        // 8 loads in flight per batch
        #pragma unroll
        for (int u = 0; u < 8; ++u) v[u] = rp4[(it0 + u) * 64 + lane];
        #pragma unroll
        for (int u = 0; u < 8; ++u) {
            const int it = it0 + u;
            const bool tgt_here = (it == it_t) && (lane == l_t);
            #pragma unroll
            for (int j = 0; j < 4; ++j) {
                const bool pred = (v[u][j] >= THRESH) && !(tgt_here && j == j_t);
                const unsigned long long bal = __ballot(pred);
                if (pred) {
                    const unsigned rank = __builtin_amdgcn_mbcnt_hi(
                        (unsigned)(bal >> 32),
                        __builtin_amdgcn_mbcnt_lo((unsigned)bal, 0u));
                    const unsigned slot = cnt + rank;
                    if (slot < CAPW) list[slot] = f2key(v[u][j]);
                }
                cnt += (unsigned)__popcll(bal);   // SGPR add, stays uniform
            }
        }
    }
    const unsigned C = cnt;                  // exact count (overflow detectable)

    const float pos = rp[target];            // hoisted: latency hidden under select

    float loss = 0.0f;
    bool have = false;

    if (C >= K_SEL && C <= CAPW) {
        wave_lgkm_wait();                    // list writes visible to own wave

        unsigned keys[8];
        #pragma unroll
        for (int it = 0; it < 8; ++it) {
            const unsigned i = lane + it * 64u;
            keys[it] = (i < C) ? list[i] : 0u;     // pad with 0 = min key, never matches
        }

        // ---- ballot bit-walk: k-th largest key, exact under ties ----
        // All real keys have bit31 set (positive floats); pad zeros never match.
        unsigned pfx = 0u, kr = K_SEL;
        #pragma unroll
        for (int p = 31; p >= 0; --p) {
            const unsigned want = (pfx << 1) | 1u;
            unsigned c1 = 0;
            #pragma unroll
            for (int j = 0; j < 8; ++j)
                c1 += (unsigned)__popcll(__ballot((keys[j] >> p) == want));
            if (c1 >= kr) pfx = want;
            else { kr -= c1; pfx <<= 1; }
        }
        const unsigned tkey = pfx, krem = kr;

        int facc = 0;                              // fixed-point, order-independent
        #pragma unroll
        for (int it = 0; it < 8; ++it) {
            unsigned k = keys[it];
            if ((lane + it * 64u) < C && k > tkey) {
                float ww = key2f(k) + 1.0f;
                facc += (int)(ww * ww * SCALE + 0.5f);
            }
        }
        #pragma unroll
        for (int off = 32; off > 0; off >>= 1) facc += __shfl_down(facc, off);
        if (lane == 0) {
            float tv    = key2f(tkey) + 1.0f;
            float total = (float)facc * (1.0f / SCALE) + (float)krem * tv * tv;
            float pd    = pos - 1.0f;
            loss = DELTA_W * pd * pd + total * (1.0f / (float)K_SEL);
            have = true;
        }
    } else {
        // ---- fallback: exact full-row radix (never taken for Gaussian bench data) ----
        unsigned prefix = 0u, kr = K_SEL;
        for (int pass = 0; pass < 4; ++pass) {
            *reinterpret_cast<uint4*>(&hist[lane * 4]) = make_uint4(0, 0, 0, 0);
            wave_lgkm_wait();
            const int shift = 24 - 8 * pass;
            for (int it = 0; it < N / 64; ++it) {
                int i = lane + it * 64;
                unsigned k = f2key(rp[i]);
                if (i == target) k = 0u;
                bool mm = (pass == 0) || ((k >> (shift + 8)) == prefix);
                if (mm) atomicAdd(&hist[(k >> shift) & 0xFFu], 1u);
            }
            wave_lgkm_wait();
            uint4 h = *reinterpret_cast<const uint4*>(&hist[lane * 4]);
            unsigned hb[4] = {h.x, h.y, h.z, h.w};
            unsigned s_local = hb[0] + hb[1] + hb[2] + hb[3];
            unsigned suf = s_local;
            #pragma unroll
            for (int off = 1; off < 64; off <<= 1) {
                unsigned o = __shfl_down(suf, off);
                suf += (lane + off < 64) ? o : 0u;
            }
            unsigned acc_above = suf - s_local;
            int foundc = -1; unsigned f_abv = 0;
            #pragma unroll
            for (int c = 3; c >= 0; --c) {
                unsigned S = acc_above + hb[c];
                if (acc_above < kr && S >= kr) { foundc = c; f_abv = acc_above; }
                acc_above = S;
            }
            bool win = (foundc >= 0);
            unsigned long long bal = __ballot(win);
            int wl = __ffsll((long long)bal) - 1;
            unsigned np = win ? ((prefix << 8) | (unsigned)(lane * 4 + foundc)) : 0u;
            unsigned nk = win ? (kr - f_abv) : 0u;
            prefix = __shfl(np, wl);
            kr     = __shfl(nk, wl);
        }
        const unsigned tkey = prefix, krem = kr;

        int facc = 0;
        for (int it = 0; it < N / 64; ++it) {
            int i = lane + it * 64;
            unsigned k = f2key(rp[i]);
            if (i == target) k = 0u;
            if (k > tkey) { float ww = key2f(k) + 1.0f; facc += (int)(ww * ww * SCALE + 0.5f); }
        }
        #pragma unroll
        for (int off = 32; off > 0; off >>= 1) facc += __shfl_down(facc, off);
        if (lane == 0) {
            float tv    = key2f(tkey) + 1.0f;
            float total = (float)facc * (1.0f / SCALE) + (float)krem * tv * tv;
            float pd    = pos - 1.0f;
            loss = DELTA_W * pd * pd + total * (1.0f / (float)K_SEL);
            have = true;
        }
    }

    if (have) row_loss[row] = loss;   // idempotent: safe to launch multiple times
}

__global__ __launch_bounds__(256) void final_reduce(
    const float* __restrict__ rl, float* __restrict__ out)
{
    int tid = threadIdx.x;
    float s = 0.0f;
    for (int i = tid; i < M; i += 256) s += rl[i];   // fixed order -> deterministic
    __shared__ float wp[4];
    int lane = tid & 63, wv = tid >> 6;
    #pragma unroll
    for (int off = 32; off > 0; off >>= 1) s += __shfl_down(s, off);
    if (lane == 0) wp[wv] = s;
    __syncthreads();
    if (tid == 0) out[0] = (wp[0] + wp[1] + wp[2] + wp[3]) / (float)M;
}

extern "C" void kernel_launch(void* const* d_in, const int* in_sizes, int n_in,
                              void* d_out, int out_size, void* d_ws, size_t ws_size,
                              hipStream_t stream) {
    const float* inp = (const float*)d_in[0];
    const int*   tgt = (const int*)d_in[1];
    float* out = (float*)d_out;
    float* row_loss = (float*)d_ws;      // 16 KiB of workspace

    // PROBE round: fused launched 3x (idempotent). T = 3F' + fin; R13's F+fin=62.8
    // pins both F' and fin. Next round reverts to single launch.
    fused_row_loss<<<M / 4, NT, 0, stream>>>(inp, tgt, row_loss);
    fused_row_loss<<<M / 4, NT, 0, stream>>>(inp, tgt, row_loss);
    fused_row_loss<<<M / 4, NT, 0, stream>>>(inp, tgt, row_loss);
    final_reduce<<<1, 256, 0, stream>>>(row_loss, out);
}

// Round 17
// 60.615 us; speedup vs baseline: 2.9044x; 2.9044x over previous
//
#include <hip/hip_runtime.h>

// inputs: [M=4096, N=16384] fp32 logits; targets: [M] int32; k = int(0.01*(N-1)) = 163
#define M        4096
#define N        16384
#define K_SEL    163
#define DELTA_W  5.0f
#define NT       256
#define CAPW     512           // per-row candidate cap (mean 373, sd 19; 7.4 sigma)
#define SCALE    4096.0f       // fixed-point for hard-negative sum (order-independent)
#define THRESH   2.0f          // E[count(x>=2)] = 373 per row; 11 sigma above K_SEL

typedef float vfloat4 __attribute__((ext_vector_type(4)));

// Order-preserving float<->uint32 key (ascending float <-> ascending key)
__device__ __forceinline__ unsigned f2key(float x) {
    unsigned u = __float_as_uint(x);
    return u ^ ((unsigned)((int)u >> 31) | 0x80000000u);
}
__device__ __forceinline__ float key2f(unsigned k) {
    unsigned u = k ^ (~(unsigned)((int)k >> 31) | 0x80000000u);
    return __uint_as_float(u);
}
__device__ __forceinline__ void wave_lgkm_wait() {
    asm volatile("s_waitcnt lgkmcnt(0)" ::: "memory");
}

// ---------- Fused kernel: wave-per-row stream -> LDS list -> ballot bit-walk ----------
// Streaming start-chunk staggered by (row & 63): de-phases the 4096 concurrent row
// streams across HBM channels (all rows are 64KB-aligned -> lockstep offsets would
// hit the same channel subset simultaneously). List order changes; select is
// order-independent so the result is bit-identical.
// Target handled analytically in the walk (no per-iteration exclusion check).
__global__ __launch_bounds__(NT, 4) void fused_row_loss(
    const float* __restrict__ inp, const int* __restrict__ tgt,
    float* __restrict__ row_loss)
{
    __shared__ unsigned hist_all[4][256];   // used by fallback path only
    __shared__ unsigned list_all[4][CAPW];  // wave-private 2 KiB (keys)
    const int lane = threadIdx.x & 63;
    const int wv   = threadIdx.x >> 6;
    const int row  = blockIdx.x * 4 + wv;
    unsigned* hist = hist_all[wv];
    unsigned* list = list_all[wv];
    const float* rp = inp + (size_t)row * N;
    const vfloat4* rp4 = reinterpret_cast<const vfloat4*>(rp);
    const int target = tgt[row];
    const int phase  = row & 63;             // channel-dephasing start chunk

    // ---- Phase 1: stream row (rotated); push ALL x>=THRESH candidates ----
    unsigned cnt = 0;                        // wave-uniform running candidate count
    #pragma unroll
    for (int it0 = 0; it0 < 64; it0 += 8) {
        vfloat4 v[8];                        // 8 loads in flight per batch
        #pragma unroll
        for (int u = 0; u < 8; ++u) {
            const int it = (it0 + u + phase) & 63;
            v[u] = rp4[it * 64 + lane];
        }
        #pragma unroll
        for (int u = 0; u < 8; ++u) {
            #pragma unroll
            for (int j = 0; j < 4; ++j) {
                const bool pred = (v[u][j] >= THRESH);
                const unsigned long long bal = __ballot(pred);
                if (pred) {
                    const unsigned rank = __builtin_amdgcn_mbcnt_hi(
                        (unsigned)(bal >> 32),
                        __builtin_amdgcn_mbcnt_lo((unsigned)bal, 0u));
                    const unsigned slot = cnt + rank;
                    if (slot < CAPW) list[slot] = f2key(v[u][j]);
                }
                cnt += (unsigned)__popcll(bal);   // SGPR add, stays uniform
            }
        }
    }
    const unsigned C = cnt;                  // exact count incl. target (detectable)

    const float pos  = rp[target];
    const bool  tk_in = (pos >= THRESH);     // target present in list?
    const unsigned tk = f2key(pos);
    const unsigned C_eff = C - (tk_in ? 1u : 0u);

    float loss = 0.0f;
    bool have = false;

    if (C_eff >= K_SEL && C <= CAPW) {
        wave_lgkm_wait();                    // list writes visible to own wave

        unsigned keys[8];
        #pragma unroll
        for (int it = 0; it < 8; ++it) {
            const unsigned i = lane + it * 64u;
            keys[it] = (i < C) ? list[i] : 0u;     // pad 0 = min key, never matches walk
        }

        // ---- ballot bit-walk for k-th largest, target excised analytically ----
        unsigned pfx = 0u, kr = K_SEL;
        #pragma unroll
        for (int p = 31; p >= 0; --p) {
            const unsigned want = (pfx << 1) | 1u;
            unsigned c1 = 0;
            #pragma unroll
            for (int j = 0; j < 8; ++j)
                c1 += (unsigned)__popcll(__ballot((keys[j] >> p) == want));
            c1 -= (tk_in && ((tk >> p) == want)) ? 1u : 0u;   // remove target instance
            if (c1 >= kr) pfx = want;
            else { kr -= c1; pfx <<= 1; }
        }
        const unsigned tkey = pfx, krem = kr;

        int facc = 0;                              // fixed-point, order-independent
        #pragma unroll
        for (int it = 0; it < 8; ++it) {
            unsigned k = keys[it];
            if (k > tkey) {                        // pads (0) can never exceed tkey
                float ww = key2f(k) + 1.0f;
                facc += (int)(ww * ww * SCALE + 0.5f);
            }
        }
        #pragma unroll
        for (int off = 32; off > 0; off >>= 1) facc += __shfl_down(facc, off);
        if (lane == 0) {
            if (tk_in && tk > tkey) {              // excise target's contribution
                float wt = pos + 1.0f;
                facc -= (int)(wt * wt * SCALE + 0.5f);   // exact: same quantization
            }
            float tv    = key2f(tkey) + 1.0f;
            float total = (float)facc * (1.0f / SCALE) + (float)krem * tv * tv;
            float pd    = pos - 1.0f;
            loss = DELTA_W * pd * pd + total * (1.0f / (float)K_SEL);
            have = true;
        }
    } else {
        // ---- fallback: exact full-row radix (never taken for Gaussian bench data) ----
        unsigned prefix = 0u, kr = K_SEL;
        for (int pass = 0; pass < 4; ++pass) {
            *reinterpret_cast<uint4*>(&hist[lane * 4]) = make_uint4(0, 0, 0, 0);
            wave_lgkm_wait();
            const int shift = 24 - 8 * pass;
            for (int it = 0; it < N / 64; ++it) {
                int i = lane + it * 64;
                unsigned k = f2key(rp[i]);
                if (i == target) k = 0u;
                bool mm = (pass == 0) || ((k >> (shift + 8)) == prefix);
                if (mm) atomicAdd(&hist[(k >> shift) & 0xFFu], 1u);
            }
            wave_lgkm_wait();
            uint4 h = *reinterpret_cast<const uint4*>(&hist[lane * 4]);
            unsigned hb[4] = {h.x, h.y, h.z, h.w};
            unsigned s_local = hb[0] + hb[1] + hb[2] + hb[3];
            unsigned suf = s_local;
            #pragma unroll
            for (int off = 1; off < 64; off <<= 1) {
                unsigned o = __shfl_down(suf, off);
                suf += (lane + off < 64) ? o : 0u;
            }
            unsigned acc_above = suf - s_local;
            int foundc = -1; unsigned f_abv = 0;
            #pragma unroll
            for (int c = 3; c >= 0; --c) {
                unsigned S = acc_above + hb[c];
                if (acc_above < kr && S >= kr) { foundc = c; f_abv = acc_above; }
                acc_above = S;
            }
            bool win = (foundc >= 0);
            unsigned long long bal = __ballot(win);
            int wl = __ffsll((long long)bal) - 1;
            unsigned np = win ? ((prefix << 8) | (unsigned)(lane * 4 + foundc)) : 0u;
            unsigned nk = win ? (kr - f_abv) : 0u;
            prefix = __shfl(np, wl);
            kr     = __shfl(nk, wl);
        }
        const unsigned tkey = prefix, krem = kr;

        int facc = 0;
        for (int it = 0; it < N / 64; ++it) {
            int i = lane + it * 64;
            unsigned k = f2key(rp[i]);
            if (i == target) k = 0u;
            if (k > tkey) { float ww = key2f(k) + 1.0f; facc += (int)(ww * ww * SCALE + 0.5f); }
        }
        #pragma unroll
        for (int off = 32; off > 0; off >>= 1) facc += __shfl_down(facc, off);
        if (lane == 0) {
            float tv    = key2f(tkey) + 1.0f;
            float total = (float)facc * (1.0f / SCALE) + (float)krem * tv * tv;
            float pd    = pos - 1.0f;
            loss = DELTA_W * pd * pd + total * (1.0f / (float)K_SEL);
            have = true;
        }
    }

    if (have) row_loss[row] = loss;
}

__global__ __launch_bounds__(256) void final_reduce(
    const float* __restrict__ rl, float* __restrict__ out)
{
    int tid = threadIdx.x;
    float s = 0.0f;
    for (int i = tid; i < M; i += 256) s += rl[i];   // fixed order -> deterministic
    __shared__ float wp[4];
    int lane = tid & 63, wv = tid >> 6;
    #pragma unroll
    for (int off = 32; off > 0; off >>= 1) s += __shfl_down(s, off);
    if (lane == 0) wp[wv] = s;
    __syncthreads();
    if (tid == 0) out[0] = (wp[0] + wp[1] + wp[2] + wp[3]) / (float)M;
}

extern "C" void kernel_launch(void* const* d_in, const int* in_sizes, int n_in,
                              void* d_out, int out_size, void* d_ws, size_t ws_size,
                              hipStream_t stream) {
    const float* inp = (const float*)d_in[0];
    const int*   tgt = (const int*)d_in[1];
    float* out = (float*)d_out;
    float* row_loss = (float*)d_ws;      // 16 KiB of workspace

    fused_row_loss<<<M / 4, NT, 0, stream>>>(inp, tgt, row_loss);
    final_reduce<<<1, 256, 0, stream>>>(row_loss, out);
}

// Round 18
// 58.409 us; speedup vs baseline: 3.0141x; 1.0378x over previous
//
#include <hip/hip_runtime.h>

// inputs: [M=4096, N=16384] fp32 logits; targets: [M] int32; k = int(0.01*(N-1)) = 163
#define M        4096
#define N        16384
#define K_SEL    163
#define DELTA_W  5.0f
#define NT       256
#define CAPW     512           // per-row candidate cap (mean 373, sd 19; 7.4 sigma)
#define SCALE    4096.0f       // fixed-point for hard-negative sum (order-independent)
#define THRESH   2.0f          // E[count(x>=2)] = 373 per row; 11 sigma above K_SEL

typedef float vfloat4 __attribute__((ext_vector_type(4)));

// Order-preserving float<->uint32 key (ascending float <-> ascending key)
__device__ __forceinline__ unsigned f2key(float x) {
    unsigned u = __float_as_uint(x);
    return u ^ ((unsigned)((int)u >> 31) | 0x80000000u);
}
__device__ __forceinline__ float key2f(unsigned k) {
    unsigned u = k ^ (~(unsigned)((int)k >> 31) | 0x80000000u);
    return __uint_as_float(u);
}
__device__ __forceinline__ void wave_lgkm_wait() {
    asm volatile("s_waitcnt lgkmcnt(0)" ::: "memory");
}

// ---------- Fused kernel: wave-per-row stream -> LDS list -> ballot bit-walk ----------
// Streaming loads are NONTEMPORAL: input (256MB) streams read-once; nt avoids L2
// self-eviction thrash and serves replays from the 256MB L3 where the input fits.
// Target handled analytically in the walk. Select is order-independent and exact.
__global__ __launch_bounds__(NT, 4) void fused_row_loss(
    const float* __restrict__ inp, const int* __restrict__ tgt,
    float* __restrict__ row_loss)
{
    __shared__ unsigned hist_all[4][256];   // used by fallback path only
    __shared__ unsigned list_all[4][CAPW];  // wave-private 2 KiB (keys)
    const int lane = threadIdx.x & 63;
    const int wv   = threadIdx.x >> 6;
    const int row  = blockIdx.x * 4 + wv;
    unsigned* hist = hist_all[wv];
    unsigned* list = list_all[wv];
    const float* rp = inp + (size_t)row * N;
    const vfloat4* rp4 = reinterpret_cast<const vfloat4*>(rp);
    const int target = tgt[row];

    // ---- Phase 1: stream row; push ALL x>=THRESH candidates to LDS list ----
    unsigned cnt = 0;                        // wave-uniform running candidate count
    #pragma unroll
    for (int it0 = 0; it0 < 64; it0 += 8) {
        vfloat4 v[8];                        // 8 nt-loads in flight per batch
        #pragma unroll
        for (int u = 0; u < 8; ++u)
            v[u] = __builtin_nontemporal_load(&rp4[(it0 + u) * 64 + lane]);
        #pragma unroll
        for (int u = 0; u < 8; ++u) {
            #pragma unroll
            for (int j = 0; j < 4; ++j) {
                const bool pred = (v[u][j] >= THRESH);
                const unsigned long long bal = __ballot(pred);
                if (pred) {
                    const unsigned rank = __builtin_amdgcn_mbcnt_hi(
                        (unsigned)(bal >> 32),
                        __builtin_amdgcn_mbcnt_lo((unsigned)bal, 0u));
                    const unsigned slot = cnt + rank;
                    if (slot < CAPW) list[slot] = f2key(v[u][j]);
                }
                cnt += (unsigned)__popcll(bal);   // SGPR add, stays uniform
            }
        }
    }
    const unsigned C = cnt;                  // exact count incl. target (detectable)

    const float pos  = rp[target];
    const bool  tk_in = (pos >= THRESH);     // target present in list?
    const unsigned tk = f2key(pos);
    const unsigned C_eff = C - (tk_in ? 1u : 0u);

    float loss = 0.0f;
    bool have = false;

    if (C_eff >= K_SEL && C <= CAPW) {
        wave_lgkm_wait();                    // list writes visible to own wave

        unsigned keys[8];
        #pragma unroll
        for (int it = 0; it < 8; ++it) {
            const unsigned i = lane + it * 64u;
            keys[it] = (i < C) ? list[i] : 0u;     // pad 0 = min key, never matches walk
        }

        // ---- ballot bit-walk for k-th largest, target excised analytically ----
        unsigned pfx = 0u, kr = K_SEL;
        #pragma unroll
        for (int p = 31; p >= 0; --p) {
            const unsigned want = (pfx << 1) | 1u;
            unsigned c1 = 0;
            #pragma unroll
            for (int j = 0; j < 8; ++j)
                c1 += (unsigned)__popcll(__ballot((keys[j] >> p) == want));
            c1 -= (tk_in && ((tk >> p) == want)) ? 1u : 0u;   // remove target instance
            if (c1 >= kr) pfx = want;
            else { kr -= c1; pfx <<= 1; }
        }
        const unsigned tkey = pfx, krem = kr;

        int facc = 0;                              // fixed-point, order-independent
        #pragma unroll
        for (int it = 0; it < 8; ++it) {
            unsigned k = keys[it];
            if (k > tkey) {                        // pads (0) can never exceed tkey
                float ww = key2f(k) + 1.0f;
                facc += (int)(ww * ww * SCALE + 0.5f);
            }
        }
        #pragma unroll
        for (int off = 32; off > 0; off >>= 1) facc += __shfl_down(facc, off);
        if (lane == 0) {
            if (tk_in && tk > tkey) {              // excise target's contribution
                float wt = pos + 1.0f;
                facc -= (int)(wt * wt * SCALE + 0.5f);   // exact: same quantization
            }
            float tv    = key2f(tkey) + 1.0f;
            float total = (float)facc * (1.0f / SCALE) + (float)krem * tv * tv;
            float pd    = pos - 1.0f;
            loss = DELTA_W * pd * pd + total * (1.0f / (float)K_SEL);
            have = true;
        }
    } else {
        // ---- fallback: exact full-row radix (never taken for Gaussian bench data) ----
        unsigned prefix = 0u, kr = K_SEL;
        for (int pass = 0; pass < 4; ++pass) {
            *reinterpret_cast<uint4*>(&hist[lane * 4]) = make_uint4(0, 0, 0, 0);
            wave_lgkm_wait();
            const int shift = 24 - 8 * pass;
            for (int it = 0; it < N / 64; ++it) {
                int i = lane + it * 64;
                unsigned k = f2key(rp[i]);
                if (i == target) k = 0u;
                bool mm = (pass == 0) || ((k >> (shift + 8)) == prefix);
                if (mm) atomicAdd(&hist[(k >> shift) & 0xFFu], 1u);
            }
            wave_lgkm_wait();
            uint4 h = *reinterpret_cast<const uint4*>(&hist[lane * 4]);
            unsigned hb[4] = {h.x, h.y, h.z, h.w};
            unsigned s_local = hb[0] + hb[1] + hb[2] + hb[3];
            unsigned suf = s_local;
            #pragma unroll
            for (int off = 1; off < 64; off <<= 1) {
                unsigned o = __shfl_down(suf, off);
                suf += (lane + off < 64) ? o : 0u;
            }
            unsigned acc_above = suf - s_local;
            int foundc = -1; unsigned f_abv = 0;
            #pragma unroll
            for (int c = 3; c >= 0; --c) {
                unsigned S = acc_above + hb[c];
                if (acc_above < kr && S >= kr) { foundc = c; f_abv = acc_above; }
                acc_above = S;
            }
            bool win = (foundc >= 0);
            unsigned long long bal = __ballot(win);
            int wl = __ffsll((long long)bal) - 1;
            unsigned np = win ? ((prefix << 8) | (unsigned)(lane * 4 + foundc)) : 0u;
            unsigned nk = win ? (kr - f_abv) : 0u;
            prefix = __shfl(np, wl);
            kr     = __shfl(nk, wl);
        }
        const unsigned tkey = prefix, krem = kr;

        int facc = 0;
        for (int it = 0; it < N / 64; ++it) {
            int i = lane + it * 64;
            unsigned k = f2key(rp[i]);
            if (i == target) k = 0u;
            if (k > tkey) { float ww = key2f(k) + 1.0f; facc += (int)(ww * ww * SCALE + 0.5f); }
        }
        #pragma unroll
        for (int off = 32; off > 0; off >>= 1) facc += __shfl_down(facc, off);
        if (lane == 0) {
            float tv    = key2f(tkey) + 1.0f;
            float total = (float)facc * (1.0f / SCALE) + (float)krem * tv * tv;
            float pd    = pos - 1.0f;
            loss = DELTA_W * pd * pd + total * (1.0f / (float)K_SEL);
            have = true;
        }
    }

    if (have) row_loss[row] = loss;
}

// 1024-thread final reduce: 4 loads/thread, short latency chain, fixed order.
__global__ __launch_bounds__(1024) void final_reduce(
    const float* __restrict__ rl, float* __restrict__ out)
{
    const int tid = threadIdx.x;
    float s = 0.0f;
    #pragma unroll
    for (int i = 0; i < 4; ++i) s += rl[tid + i * 1024];
    __shared__ float wp[16];
    const int lane = tid & 63, wv = tid >> 6;
    #pragma unroll
    for (int off = 32; off > 0; off >>= 1) s += __shfl_down(s, off);
    if (lane == 0) wp[wv] = s;
    __syncthreads();
    if (tid == 0) {
        float t = 0.0f;
        #pragma unroll
        for (int i = 0; i < 16; ++i) t += wp[i];
        out[0] = t / (float)M;
    }
}

extern "C" void kernel_launch(void* const* d_in, const int* in_sizes, int n_in,
                              void* d_out, int out_size, void* d_ws, size_t ws_size,
                              hipStream_t stream) {
    const float* inp = (const float*)d_in[0];
    const int*   tgt = (const int*)d_in[1];
    float* out = (float*)d_out;
    float* row_loss = (float*)d_ws;      // 16 KiB of workspace

    fused_row_loss<<<M / 4, NT, 0, stream>>>(inp, tgt, row_loss);
    final_reduce<<<1, 1024, 0, stream>>>(row_loss, out);
}